// Round 3
// baseline (450.119 us; speedup 1.0000x reference)
//
#include <hip/hip_runtime.h>

#define N_NODES 100000
#define N_EDGES 1600000
#define D 64
#define NP 8              // partial-histogram tables

#define SCAN_ELEMS 1024
#define SCAN_NBLOCKS 98   // ceil(100000/1024)

// -------- hist: privatized deg[row] += w; rank[e] = counts[col]++ --------
__global__ void hist_kernel(const int* __restrict__ row, const int* __restrict__ col,
                            const float* __restrict__ w,
                            float* __restrict__ deg_p, int* __restrict__ counts_p,
                            int* __restrict__ rank) {
    int e = blockIdx.x * blockDim.x + threadIdx.x;
    if (e >= N_EDGES) return;
    int p = blockIdx.x & (NP - 1);
    atomicAdd(&deg_p[p * N_NODES + row[e]], w[e]);
    rank[e] = atomicAdd(&counts_p[p * N_NODES + col[e]], 1);
}

// -------- dinv[i] = rsqrt(sum of partial degs) --------
__global__ void dinv_kernel(const float* __restrict__ deg_p, float* __restrict__ dinv) {
    int i = blockIdx.x * blockDim.x + threadIdx.x;
    if (i >= N_NODES) return;
    float d = 0.f;
    #pragma unroll
    for (int p = 0; p < NP; ++p) d += deg_p[p * N_NODES + i];
    dinv[i] = d > 0.0f ? rsqrtf(d) : 0.0f;
}

// -------- per-col exclusive prefix over the NP tables + totals --------
__global__ void pre_kernel(const int* __restrict__ counts_p,
                           int* __restrict__ pre, int* __restrict__ totals) {
    int c = blockIdx.x * blockDim.x + threadIdx.x;
    if (c >= N_NODES) return;
    int s = 0;
    #pragma unroll
    for (int p = 0; p < NP; ++p) {
        int v = counts_p[p * N_NODES + c];
        pre[p * N_NODES + c] = s;
        s += v;
    }
    totals[c] = s;
}

// -------- scan phase 1: per-block sums of totals --------
__global__ __launch_bounds__(256) void scan_sums(const int* __restrict__ totals,
                                                 int* __restrict__ blockSums) {
    __shared__ int lds[256];
    int t = threadIdx.x;
    int base = blockIdx.x * SCAN_ELEMS + t * 4;
    int s = 0;
    #pragma unroll
    for (int i = 0; i < 4; ++i) {
        int idx = base + i;
        if (idx < N_NODES) s += totals[idx];
    }
    lds[t] = s;
    __syncthreads();
    for (int off = 128; off > 0; off >>= 1) {
        if (t < off) lds[t] += lds[t + off];
        __syncthreads();
    }
    if (t == 0) blockSums[blockIdx.x] = lds[0];
}

// -------- scan phase 2: exclusive scan of block sums --------
__global__ __launch_bounds__(128) void scan_offsets(int* __restrict__ blockSums) {
    __shared__ int lds[128];
    int t = threadIdx.x;
    int v = (t < SCAN_NBLOCKS) ? blockSums[t] : 0;
    lds[t] = v;
    __syncthreads();
    for (int off = 1; off < 128; off <<= 1) {
        int u = (t >= off) ? lds[t - off] : 0;
        __syncthreads();
        lds[t] += u;
        __syncthreads();
    }
    if (t < SCAN_NBLOCKS) blockSums[t] = (t > 0) ? lds[t - 1] : 0;
}

// -------- scan phase 3: emit exclusive starts[] --------
__global__ __launch_bounds__(256) void scan_emit(const int* __restrict__ totals,
                                                 const int* __restrict__ blockSums,
                                                 int* __restrict__ starts) {
    __shared__ int lds[256];
    int t = threadIdx.x;
    int base = blockIdx.x * SCAN_ELEMS + t * 4;
    int c[4];
    int s = 0;
    #pragma unroll
    for (int i = 0; i < 4; ++i) {
        int idx = base + i;
        c[i] = (idx < N_NODES) ? totals[idx] : 0;
        s += c[i];
    }
    lds[t] = s;
    __syncthreads();
    for (int off = 1; off < 256; off <<= 1) {
        int u = (t >= off) ? lds[t - off] : 0;
        __syncthreads();
        lds[t] += u;
        __syncthreads();
    }
    int excl = ((t > 0) ? lds[t - 1] : 0) + blockSums[blockIdx.x];
    #pragma unroll
    for (int i = 0; i < 4; ++i) {
        int idx = base + i;
        if (idx < N_NODES) starts[idx] = excl;
        excl += c[i];
    }
}

// -------- bucket: deterministic positions, NO atomics --------
__global__ void bucket_kernel(const int* __restrict__ row, const int* __restrict__ col,
                              const float* __restrict__ w, const float* __restrict__ dinv,
                              const int* __restrict__ starts, const int* __restrict__ pre,
                              const int* __restrict__ rank, float2* __restrict__ recs) {
    int e = blockIdx.x * blockDim.x + threadIdx.x;
    if (e >= N_EDGES) return;
    int p = blockIdx.x & (NP - 1);   // must match hist_kernel's mapping
    int r = row[e];
    int c = col[e];
    float cf = dinv[r] * w[e];       // final coeff = -dinv[c] * cf, applied in gather
    int pos = starts[c] + pre[p * N_NODES + c] + rank[e];
    recs[pos] = make_float2(__int_as_float(r), cf);
}

// -------- fused gather + matmul: out = x@W0 + Tx1@W1 + b --------
// 256 threads = 16 nodes x 16 lanes (each lane owns a float4 chunk).
__global__ __launch_bounds__(256) void gather_out_kernel(
        const float2* __restrict__ recs, const int* __restrict__ starts,
        const int* __restrict__ totals, const float* __restrict__ dinv,
        const float* __restrict__ x,
        const float* __restrict__ W0, const float* __restrict__ W1,
        const float* __restrict__ b, float* __restrict__ out) {
    __shared__ float W0s[D * D];
    __shared__ float W1s[D * D];
    __shared__ float xs[16][D];
    __shared__ float ts[16][D];
    int tid = threadIdx.x;

    // Stage weights (issue early; consumed after the barrier).
    for (int i = tid * 4; i < D * D; i += 256 * 4) {
        *(float4*)(W0s + i) = *(const float4*)(W0 + i);
        *(float4*)(W1s + i) = *(const float4*)(W1 + i);
    }

    int g = tid >> 4;
    int lane4 = (tid & 15) << 2;
    int n = blockIdx.x * 16 + g;
    int s = starts[n];
    int cnt = totals[n];
    float di = dinv[n];

    float4 acc = make_float4(0.f, 0.f, 0.f, 0.f);
    for (int k = 0; k < cnt; ++k) {
        float2 rec = recs[s + k];
        int r = __float_as_int(rec.x);
        float cf = rec.y;
        const float4 xv = *(const float4*)(x + (size_t)r * D + lane4);
        acc.x += cf * xv.x;
        acc.y += cf * xv.y;
        acc.z += cf * xv.z;
        acc.w += cf * xv.w;
    }
    // Tx1 chunk = -dinv[n] * acc
    acc.x *= -di; acc.y *= -di; acc.z *= -di; acc.w *= -di;
    *(float4*)(&ts[g][lane4]) = acc;
    *(float4*)(&xs[g][lane4]) = *(const float4*)(x + (size_t)n * D + lane4);
    __syncthreads();

    float4 o = *(const float4*)(b + lane4);
    #pragma unroll
    for (int k = 0; k < D; ++k) {
        float a = xs[g][k];
        float t = ts[g][k];
        float4 w0 = *(const float4*)(W0s + k * D + lane4);
        float4 w1 = *(const float4*)(W1s + k * D + lane4);
        o.x += a * w0.x + t * w1.x;
        o.y += a * w0.y + t * w1.y;
        o.z += a * w0.z + t * w1.z;
        o.w += a * w0.w + t * w1.w;
    }
    *(float4*)(out + (size_t)n * D + lane4) = o;
}

extern "C" void kernel_launch(void* const* d_in, const int* in_sizes, int n_in,
                              void* d_out, int out_size, void* d_ws, size_t ws_size,
                              hipStream_t stream) {
    const float* x    = (const float*)d_in[0];
    const int*   eidx = (const int*)d_in[1];   // [2, E]: row then col
    const float* ew   = (const float*)d_in[2];
    const float* W0   = (const float*)d_in[3];
    const float* W1   = (const float*)d_in[4];
    const float* b    = (const float*)d_in[5];
    float* out = (float*)d_out;

    const int* row = eidx;
    const int* col = eidx + N_EDGES;

    // Workspace layout (words = 4B). recs region is dead until bucket_kernel,
    // so the partial histogram tables alias it.
    float*  base      = (float*)d_ws;
    float2* recs      = (float2*)base;                         // E float2 = 3.2M words
    float*  deg_p     = base;                                  // alias: NP*N words
    int*    counts_p  = (int*)(base + (size_t)NP * N_NODES);   // alias: NP*N words
    float*  dinv      = base + (size_t)2 * N_EDGES;            // N
    int*    totals    = (int*)(dinv + N_NODES);                // N
    int*    starts    = totals + N_NODES;                      // N
    int*    blockSums = starts + N_NODES;                      // 128
    int*    pre       = blockSums + 128;                       // NP*N
    int*    rank      = pre + (size_t)NP * N_NODES;            // E

    // Zero the partial tables (2*NP*N words = 6.4 MB).
    hipMemsetAsync(deg_p, 0, (size_t)2 * NP * N_NODES * 4, stream);

    hist_kernel<<<(N_EDGES + 255) / 256, 256, 0, stream>>>(row, col, ew,
                                                           deg_p, counts_p, rank);
    dinv_kernel<<<(N_NODES + 255) / 256, 256, 0, stream>>>(deg_p, dinv);
    pre_kernel <<<(N_NODES + 255) / 256, 256, 0, stream>>>(counts_p, pre, totals);

    scan_sums   <<<SCAN_NBLOCKS, 256, 0, stream>>>(totals, blockSums);
    scan_offsets<<<1, 128, 0, stream>>>(blockSums);
    scan_emit   <<<SCAN_NBLOCKS, 256, 0, stream>>>(totals, blockSums, starts);

    bucket_kernel<<<(N_EDGES + 255) / 256, 256, 0, stream>>>(
        row, col, ew, dinv, starts, pre, rank, recs);

    gather_out_kernel<<<N_NODES / 16, 256, 0, stream>>>(
        recs, starts, totals, dinv, x, W0, W1, b, out);
}